// Round 7
// baseline (1379.573 us; speedup 1.0000x reference)
//
#include <hip/hip_runtime.h>
#include <hip/hip_bf16.h>
#include <math.h>

#define NN 100000
#define NE 1600000
#define NP 500000
#define HD 128
#define NPB 128                    // nodes per bucket (pow2)
#define NB 782                     // ceil(NN/NPB)
#define CAP 2560                   // bucket capacity (mean 2048, +11 sigma)
#define CHUNK 4096                 // edges per binning workgroup
#define NWG 391                    // ceil(NE/CHUNK)
#define ASTR 65                    // acc LDS stride (65%32==1 -> bank = ldst+8fl+j, ~2-way)

typedef __attribute__((ext_vector_type(8))) short short8;   // 8 bf16 = 4 VGPRs
typedef __attribute__((ext_vector_type(4))) float f32x4;

// ---- bf16 helpers ----
__device__ __forceinline__ float bf_lo(unsigned int u) { return __uint_as_float(u << 16); }
__device__ __forceinline__ float bf_hi(unsigned int u) { return __uint_as_float(u & 0xffff0000u); }
__device__ __forceinline__ unsigned short bf16_rne(float f) {
  unsigned int u = __float_as_uint(f);
  u = (u + 0x7fffu + ((u >> 16) & 1u)) >> 16;
  return (unsigned short)u;
}

// ---------------- prep (fused): W1 transpose/cast + u-vectors + gcursor init ----------------
__global__ __launch_bounds__(256) void k_prep(const float* __restrict__ W1,
                                              unsigned short* __restrict__ Wt,
                                              const float* __restrict__ W2,
                                              const float* __restrict__ Wl,
                                              const float* __restrict__ b2,
                                              float* __restrict__ uv,
                                              int* __restrict__ gcursor) {
  const int blk = blockIdx.x;
  const int t = threadIdx.x;
  if (blk < 64) {
    int i = blk * 256 + t;           // 16384
    int n = i >> 7, k = i & 127;
    Wt[i] = bf16_rne(W1[k * HD + n]);
  } else if (blk == 64) {
    // u-vectors: u1 = W2@Wl[:128], u2 = W2@Wl[128:], c1/c2 = b2.Wl
    __shared__ float sh[256];
    const int half = t >> 7;
    const int k = t & 127;
    const float* wl = Wl + half * 128;
    float s = 0.f;
    for (int c = 0; c < 128; ++c) s += W2[k * HD + c] * wl[c];
    uv[half * 128 + k] = s;

    sh[t] = b2[k] * Wl[half * 128 + k];
    __syncthreads();
    for (int o = 64; o > 0; o >>= 1) {
      if ((t & 127) < o) sh[t] += sh[t + o];
      __syncthreads();
    }
    if (t == 0) uv[256] = sh[0];
    if (t == 128) uv[257] = sh[128];
  } else {
    for (int i = t; i < NB; i += 256) gcursor[i] = i * CAP;
  }
}

// ---- binA: bin edges into fixed-capacity bucket regions; 4B entry = src | (d&127)<<17 ----
// LDS bucket-sort before global scatter (R6). Unchanged this round (measurement control).
__global__ __launch_bounds__(256) void k_binA(const int* __restrict__ src,
                                              const int* __restrict__ dst,
                                              int* __restrict__ gcursor,
                                              unsigned* __restrict__ binned, int ne) {
  __shared__ int hist[1024];          // counts -> in-place exclusive scan (pad to 1024)
  __shared__ int base[NB];            // global base per bucket
  __shared__ int sc[256];             // block scan workspace
  __shared__ unsigned sortedEnt[CHUNK];
  __shared__ int sortedTgt[CHUNK];
  const int t = threadIdx.x;
  const int e0 = blockIdx.x * CHUNK;
  const int nv = (ne - e0 < CHUNK) ? (ne - e0) : CHUNK;   // valid edges this chunk

  for (int i = t; i < 1024; i += 256) hist[i] = 0;
  __syncthreads();

  int dstv[CHUNK / 256];
  int rank[CHUNK / 256];
#pragma unroll
  for (int k = 0; k < CHUNK / 256; ++k) {
    int e = e0 + k * 256 + t;
    dstv[k] = (e < ne) ? dst[e] : -1;
    rank[k] = (dstv[k] >= 0) ? atomicAdd(&hist[dstv[k] >> 7], 1) : 0;
  }
  __syncthreads();

  // global bucket bases (one atomic per non-empty bucket)
  for (int i = t; i < NB; i += 256) {
    int c = hist[i];
    base[i] = c ? atomicAdd(&gcursor[i], c) : 0;
  }

  // exclusive scan of hist[1024] (blocked, 4 slots/thread) -> hist becomes local scan
  int4 hh = *(int4*)&hist[t * 4];
  int s = hh.x + hh.y + hh.z + hh.w;
  sc[t] = s;
  __syncthreads();
#pragma unroll
  for (int o = 1; o < 256; o <<= 1) {
    int add = (t >= o) ? sc[t - o] : 0;
    __syncthreads();
    sc[t] += add;
    __syncthreads();
  }
  int ex = sc[t] - s;
  hist[t * 4 + 0] = ex;
  hist[t * 4 + 1] = ex + hh.x;
  hist[t * 4 + 2] = ex + hh.x + hh.y;
  hist[t * 4 + 3] = ex + hh.x + hh.y + hh.z;
  __syncthreads();

  // scatter into LDS in bucket-sorted order, recording global targets
#pragma unroll
  for (int k = 0; k < CHUNK / 256; ++k) {
    int d = dstv[k];
    if (d >= 0) {
      int e = e0 + k * 256 + t;
      int b = d >> 7;
      int j = hist[b] + rank[k];
      sortedEnt[j] = (unsigned)src[e] | ((unsigned)(d & 127) << 17);
      sortedTgt[j] = base[b] + rank[k];
    }
  }
  __syncthreads();

  // coalesced-run writeout
  for (int j = t; j < nv; j += 256) binned[sortedTgt[j]] = sortedEnt[j];
}

// ---------------- dinv: per-bucket degree count -> dinv (binB reduced to this) ----------------
__global__ __launch_bounds__(256) void k_dinv(const unsigned* __restrict__ binned,
                                              const int* __restrict__ gcursor,
                                              float* __restrict__ dinv) {
  __shared__ int cntS[NPB];
  const int g = blockIdx.x;
  const int t = threadIdx.x;
  if (t < NPB) cntS[t] = 0;
  __syncthreads();
  const int gbase = g * CAP;
  const int gend = gcursor[g];
  for (int i = gbase + t; i < gend; i += 256)
    atomicAdd(&cntS[binned[i] >> 17], 1);
  __syncthreads();
  const int node = g * NPB + t;
  if (t < NPB && node < NN) dinv[node] = rsqrtf((float)cntS[t] + 1.0f);
}

// ---------------- MFMA GEMM -> half-row layout ----------------
// hs split into two half-row arrays of 64 bf16 (=128B, one L2 line):
//   half h, row r, local feat c: hs[((h*NN)+r)*64 + c], global feat = h*64+c
__global__ __launch_bounds__(256) void k_gemm_mfma(const float* __restrict__ X,
                                                   const unsigned short* __restrict__ Wt,
                                                   const float* __restrict__ dinv,
                                                   unsigned short* __restrict__ hs,
                                                   int nrows) {
  const int wave = threadIdx.x >> 6;
  const int lane = threadIdx.x & 63;
  const int row0 = blockIdx.x * 64 + wave * 16;
  if (row0 >= nrows) return;
  const int lm = lane & 15;   // A-row / C-col
  const int lq = lane >> 4;   // quad

  int arow = row0 + lm;
  int arowc = arow < nrows ? arow : nrows - 1;  // clamp (stores are guarded)

  short8 afrag[4];
#pragma unroll
  for (int kc = 0; kc < 4; ++kc) {
    int k0 = kc * 32 + lq * 8;
    const float4* p = (const float4*)(X + (size_t)arowc * HD + k0);
    float4 f0 = p[0], f1 = p[1];
    short8 a;
    a[0] = (short)bf16_rne(f0.x); a[1] = (short)bf16_rne(f0.y);
    a[2] = (short)bf16_rne(f0.z); a[3] = (short)bf16_rne(f0.w);
    a[4] = (short)bf16_rne(f1.x); a[5] = (short)bf16_rne(f1.y);
    a[6] = (short)bf16_rne(f1.z); a[7] = (short)bf16_rne(f1.w);
    afrag[kc] = a;
  }

  float dv[4];
#pragma unroll
  for (int r = 0; r < 4; ++r) {
    int row = row0 + lq * 4 + r;
    dv[r] = dinv[row < nrows ? row : 0];
  }

#pragma unroll
  for (int nt = 0; nt < 8; ++nt) {
    f32x4 acc = {0.f, 0.f, 0.f, 0.f};
    const unsigned short* Wb = Wt + (size_t)(nt * 16 + lm) * HD + lq * 8;
#pragma unroll
    for (int kc = 0; kc < 4; ++kc) {
      short8 bfrag = *(const short8*)(Wb + kc * 32);
      acc = __builtin_amdgcn_mfma_f32_16x16x32_bf16(afrag[kc], bfrag, acc, 0, 0, 0);
    }
    const int half = nt >> 2;
    const int loc = (nt & 3) * 16 + lm;
#pragma unroll
    for (int r = 0; r < 4; ++r) {
      int row = row0 + lq * 4 + r;
      if (row < nrows)
        hs[((size_t)half * NN + row) * 64 + loc] = bf16_rne(acc[r] * dv[r]);
    }
  }
}

// ---------------- gatherB: bucket-centric LDS-accumulation (no col/rows/sortOrd) ----------------
// Block = (bucket, half). Walks the bucket's binned segment sequentially (coalesced-ish),
// 8 lanes load one 128B hs half-row per edge, ds_add_f32 into acc[ldst][feat].
// acc stride 65 (bank = ldst + 8*fl + j mod 32; random ldst -> ~2-way = free, m136).
// Self term = acc init from own row. Double-buffered edge loads for latency overlap.
__global__ __launch_bounds__(256) void k_gatherB(const uint4* __restrict__ hsv,
                                                 const float* __restrict__ dinv,
                                                 const unsigned* __restrict__ binned,
                                                 const int* __restrict__ gcursor,
                                                 const float* __restrict__ b1,
                                                 const float* __restrict__ uv,
                                                 float2* __restrict__ qpart) {
  __shared__ float accf[NPB * ASTR];   // 33280 B -> 4 blocks/CU
  const int half = blockIdx.x & 1;
  const int g = blockIdx.x >> 1;
  const int t = threadIdx.x;
  const int gi = t >> 3;               // edge-group 0..31
  const int fl = t & 7;                // lane in group: 16B of the 128B row
  const int node0 = g * NPB;
  const int gbase = g * CAP;
  const int cnt = gcursor[g] - gbase;
  const uint4* plane = hsv + (size_t)half * NN * 8;

  // init acc with self term: acc[n][f] = hs_half[node0+n][f]
  for (int i = t; i < NPB * 8; i += 256) {
    int n = i >> 3, c = i & 7;
    int node = node0 + n;
    float v0 = 0.f, v1 = 0.f, v2 = 0.f, v3 = 0.f, v4 = 0.f, v5 = 0.f, v6 = 0.f, v7 = 0.f;
    if (node < NN) {
      uint4 u = plane[(size_t)node * 8 + c];
      v0 = bf_lo(u.x); v1 = bf_hi(u.x); v2 = bf_lo(u.y); v3 = bf_hi(u.y);
      v4 = bf_lo(u.z); v5 = bf_hi(u.z); v6 = bf_lo(u.w); v7 = bf_hi(u.w);
    }
    float* ap = accf + n * ASTR + c * 8;
    ap[0] = v0; ap[1] = v1; ap[2] = v2; ap[3] = v3;
    ap[4] = v4; ap[5] = v5; ap[6] = v6; ap[7] = v7;
  }
  __syncthreads();

  // edge accumulation, 32 edges per round, double-buffered
  const int nr = (cnt + 31) >> 5;
  bool val = gi < cnt;
  unsigned en = val ? binned[gbase + gi] : 0u;
  uint4 u = val ? plane[(size_t)(en & 0x1FFFF) * 8 + fl] : make_uint4(0, 0, 0, 0);
  for (int r = 0; r < nr; ++r) {
    const int ei2 = (r + 1) * 32 + gi;
    const bool val2 = ei2 < cnt;
    unsigned en2 = val2 ? binned[gbase + ei2] : 0u;
    uint4 u2 = val2 ? plane[(size_t)(en2 & 0x1FFFF) * 8 + fl] : make_uint4(0, 0, 0, 0);
    if (val) {
      float* ap = accf + (int)(en >> 17) * ASTR + fl * 8;
      atomicAdd(ap + 0, bf_lo(u.x)); atomicAdd(ap + 1, bf_hi(u.x));
      atomicAdd(ap + 2, bf_lo(u.y)); atomicAdd(ap + 3, bf_hi(u.y));
      atomicAdd(ap + 4, bf_lo(u.z)); atomicAdd(ap + 5, bf_hi(u.z));
      atomicAdd(ap + 6, bf_lo(u.w)); atomicAdd(ap + 7, bf_hi(u.w));
    }
    en = en2; u = u2; val = val2;
  }
  __syncthreads();

  // epilogue: 2 threads per node (32 feats each): relu + projection -> qpart
  const int n = t >> 1;
  const int h32 = t & 1;
  const int node = node0 + n;
  if (node < NN) {
    float di = dinv[node];
    float s1 = 0.f, s2 = 0.f;
    const float* ap = accf + n * ASTR + h32 * 32;
#pragma unroll
    for (int j = 0; j < 32; ++j) {
      int f = half * 64 + h32 * 32 + j;
      float h = fmaxf(di * ap[j] + b1[f], 0.f);
      s1 += h * uv[f];
      s2 += h * uv[128 + f];
    }
    s1 += __shfl_xor(s1, 1);
    s2 += __shfl_xor(s2, 1);
    if (h32 == 0) qpart[(size_t)half * NN + node] = make_float2(di * s1, di * s2);
  }
}

// ---------------- qred: q[n] = qpart[0][n] + qpart[1][n] ----------------
__global__ void k_qred(const float2* __restrict__ qpart, float2* __restrict__ q, int n) {
  int i = blockIdx.x * 256 + threadIdx.x;
  if (i < n) {
    float2 a = qpart[i];
    float2 b = qpart[(size_t)NN + i];
    q[i] = make_float2(a.x + b.x, a.y + b.y);
  }
}

// ---------------- qaggB: conv2+score via bucket LDS-accumulation (no col) ----------------
// acc2 stride 3 (3l+c mod 32, random l -> spread). q table 800KB L2-resident.
__global__ __launch_bounds__(256) void k_qaggB(const float2* __restrict__ q,
                                               const float* __restrict__ dinv,
                                               const unsigned* __restrict__ binned,
                                               const int* __restrict__ gcursor,
                                               const float* __restrict__ uv,
                                               float2* __restrict__ sv) {
  __shared__ float acc2[NPB * 3];
  const int g = blockIdx.x;
  const int t = threadIdx.x;
  for (int i = t; i < NPB * 3; i += 256) acc2[i] = 0.f;
  __syncthreads();
  const int gbase = g * CAP;
  const int gend = gcursor[g];
  for (int i = gbase + t; i < gend; i += 256) {
    unsigned en = binned[i];
    float2 qq = q[en & 0x1FFFF];
    float* ap = acc2 + (int)(en >> 17) * 3;
    atomicAdd(ap + 0, qq.x);
    atomicAdd(ap + 1, qq.y);
  }
  __syncthreads();
  const int node = g * NPB + t;
  if (t < NPB && node < NN) {
    float di = dinv[node];
    float2 a = q[node];
    sv[node] = make_float2((acc2[t * 3] + a.x) * di + uv[256],
                           (acc2[t * 3 + 1] + a.y) * di + uv[257]);
  }
}

// ---------------- pair outputs ----------------
__global__ void k_pairs(const float2* __restrict__ s, const int* __restrict__ I,
                        const int* __restrict__ J, const float* __restrict__ blin,
                        float* __restrict__ out, int np) {
  int p = blockIdx.x * 256 + threadIdx.x;
  if (p < np) {
    float v = s[I[p]].x + s[J[p]].y + blin[0];
    out[p] = 1.f / (1.f + __expf(-v));
  }
}

extern "C" void kernel_launch(void* const* d_in, const int* in_sizes, int n_in,
                              void* d_out, int out_size, void* d_ws, size_t ws_size,
                              hipStream_t stream) {
  const float* x     = (const float*)d_in[0];
  const int*   eidx  = (const int*)d_in[1];
  const int*   Iidx  = (const int*)d_in[2];
  const int*   Jidx  = (const int*)d_in[3];
  const float* W1    = (const float*)d_in[4];
  const float* b1    = (const float*)d_in[5];
  const float* W2    = (const float*)d_in[6];
  const float* b2    = (const float*)d_in[7];
  const float* Wlin  = (const float*)d_in[8];
  const float* blin  = (const float*)d_in[9];
  const int* src = eidx;
  const int* dst = eidx + NE;

  // workspace layout: hs FIRST so half-rows are 128B-aligned (one line each)
  unsigned short* hs = (unsigned short*)d_ws;         // NN*HD bf16 = 25.6 MB (2 halves)
  float* dinv  = (float*)(hs + (size_t)NN * HD);      // 100000
  float* sv    = dinv + 100000;                       // 200000 (float2/node)
  float* qbuf  = sv + 200000;                         // 200000 (float2/node)
  float* qpart = qbuf + 200000;                       // 2*NN float2 = 400000
  float* uv    = qpart + 400000;                      // 264
  unsigned short* wt1 = (unsigned short*)(uv + 264);  // 16384 bf16
  int* gcursor = (int*)(wt1 + 16384);                 // NB (pad 784)
  unsigned* binned = (unsigned*)(gcursor + 784);      // NB*CAP x 4B

  float* out = (float*)d_out;

  // ---- prep (weight prep + cursor init, fused) ----
  k_prep<<<66, 256, 0, stream>>>(W1, wt1, W2, Wlin, b2, uv, gcursor);

  // ---- binning (fixed-capacity buckets; LDS-sorted scatter) ----
  k_binA<<<NWG, 256, 0, stream>>>(src, dst, gcursor, binned, NE);

  // ---- degree -> dinv (binB reduced to this) ----
  k_dinv<<<NB, 256, 0, stream>>>(binned, gcursor, dinv);

  // conv1 GEMM -> half-row hs
  k_gemm_mfma<<<(NN + 63) / 64, 256, 0, stream>>>(x, wt1, dinv, hs, NN);

  // conv1 aggregation + relu + score projection (bucket-centric LDS accumulation)
  k_gatherB<<<NB * 2, 256, 0, stream>>>((const uint4*)hs, dinv, binned, gcursor,
                                        b1, uv, (float2*)qpart);
  k_qred<<<(NN + 255) / 256, 256, 0, stream>>>((const float2*)qpart, (float2*)qbuf, NN);

  // conv2 + score head collapsed (bucket-centric LDS accumulation)
  k_qaggB<<<NB, 256, 0, stream>>>((const float2*)qbuf, dinv, binned, gcursor, uv,
                                  (float2*)sv);

  // pair outputs
  k_pairs<<<(NP + 255) / 256, 256, 0, stream>>>((const float2*)sv, Iidx, Jidx, blin, out, NP);
}

// Round 8
// 263.029 us; speedup vs baseline: 5.2449x; 5.2449x over previous
//
#include <hip/hip_runtime.h>
#include <hip/hip_bf16.h>
#include <math.h>

#define NN 100000
#define NE 1600000
#define NP 500000
#define HD 128
#define NPB 128                    // nodes per bucket (pow2)
#define NB 782                     // ceil(NN/NPB)
#define CAP 2560                   // bucket capacity (mean 2048, +11 sigma)
#define CHUNK 4096                 // edges per binning workgroup
#define NWG 391                    // ceil(NE/CHUNK)

typedef __attribute__((ext_vector_type(8))) short short8;   // 8 bf16 = 4 VGPRs
typedef __attribute__((ext_vector_type(4))) float f32x4;

// ---- bf16 helpers ----
__device__ __forceinline__ float bf_lo(unsigned int u) { return __uint_as_float(u << 16); }
__device__ __forceinline__ float bf_hi(unsigned int u) { return __uint_as_float(u & 0xffff0000u); }
__device__ __forceinline__ unsigned short bf16_rne(float f) {
  unsigned int u = __float_as_uint(f);
  u = (u + 0x7fffu + ((u >> 16) & 1u)) >> 16;
  return (unsigned short)u;
}
// accumulate 8 bf16 (one uint4) into ax[8]
__device__ __forceinline__ void acc_row8(float* ax, uint4 u) {
  ax[0] += bf_lo(u.x); ax[1] += bf_hi(u.x);
  ax[2] += bf_lo(u.y); ax[3] += bf_hi(u.y);
  ax[4] += bf_lo(u.z); ax[5] += bf_hi(u.z);
  ax[6] += bf_lo(u.w); ax[7] += bf_hi(u.w);
}

// ---------------- prep (fused): W1 transpose/cast + u-vectors + gcursor init ----------------
__global__ __launch_bounds__(256) void k_prep(const float* __restrict__ W1,
                                              unsigned short* __restrict__ Wt,
                                              const float* __restrict__ W2,
                                              const float* __restrict__ Wl,
                                              const float* __restrict__ b2,
                                              float* __restrict__ uv,
                                              int* __restrict__ gcursor) {
  const int blk = blockIdx.x;
  const int t = threadIdx.x;
  if (blk < 64) {
    int i = blk * 256 + t;           // 16384
    int n = i >> 7, k = i & 127;
    Wt[i] = bf16_rne(W1[k * HD + n]);
  } else if (blk == 64) {
    // u-vectors: u1 = W2@Wl[:128], u2 = W2@Wl[128:], c1/c2 = b2.Wl
    __shared__ float sh[256];
    const int half = t >> 7;
    const int k = t & 127;
    const float* wl = Wl + half * 128;
    float s = 0.f;
    for (int c = 0; c < 128; ++c) s += W2[k * HD + c] * wl[c];
    uv[half * 128 + k] = s;

    sh[t] = b2[k] * Wl[half * 128 + k];
    __syncthreads();
    for (int o = 64; o > 0; o >>= 1) {
      if ((t & 127) < o) sh[t] += sh[t + o];
      __syncthreads();
    }
    if (t == 0) uv[256] = sh[0];
    if (t == 128) uv[257] = sh[128];
  } else {
    for (int i = t; i < NB; i += 256) gcursor[i] = i * CAP;
  }
}

// ---- binA: bin edges into fixed-capacity bucket regions; 4B entry = src | (d&127)<<17 ----
// Rank captured from the pass-1 atomicAdd return (no second LDS-atomic pass). R5 version.
__global__ __launch_bounds__(256) void k_binA(const int* __restrict__ src,
                                              const int* __restrict__ dst,
                                              int* __restrict__ gcursor,
                                              unsigned* __restrict__ binned, int ne) {
  __shared__ int hist[NB];
  __shared__ int base[NB];
  const int t = threadIdx.x;
  const int e0 = blockIdx.x * CHUNK;

  for (int i = t; i < NB; i += 256) hist[i] = 0;
  __syncthreads();

  int dstv[CHUNK / 256];
  int rank[CHUNK / 256];
#pragma unroll
  for (int k = 0; k < CHUNK / 256; ++k) {
    int e = e0 + k * 256 + t;
    dstv[k] = (e < ne) ? dst[e] : -1;
    rank[k] = (dstv[k] >= 0) ? atomicAdd(&hist[dstv[k] >> 7], 1) : 0;
  }
  __syncthreads();

  for (int i = t; i < NB; i += 256) {
    int c = hist[i];
    base[i] = c ? atomicAdd(&gcursor[i], c) : 0;
  }
  __syncthreads();

#pragma unroll
  for (int k = 0; k < CHUNK / 256; ++k) {
    int d = dstv[k];
    if (d >= 0) {
      int e = e0 + k * 256 + t;
      int pos = base[d >> 7] + rank[k];
      binned[pos] = (unsigned)src[e] | ((unsigned)(d & 127) << 17);
    }
  }
}

// ---- binB: per-node count -> rows + dinv + degree-sorted order, then CSR placement ----
// Entries + per-entry ranks staged in LDS during the count pass; placement is atomic-free.
__global__ __launch_bounds__(256) void k_binB(const unsigned* __restrict__ binned,
                                              const int* __restrict__ gcursor,
                                              int2* __restrict__ rows,
                                              int* __restrict__ col,
                                              float* __restrict__ dinv,
                                              int* __restrict__ sortOrd) {
  __shared__ unsigned lbin[CAP];
  __shared__ unsigned short lrank[CAP];
  __shared__ int hcnt[NPB];
  __shared__ int sc[NPB];
  __shared__ int lcur[NPB];
  __shared__ int h64[64];
  __shared__ int s64[64];
  const int b = blockIdx.x;
  const int t = threadIdx.x;
  const int node0 = b * NPB;
  const int node1 = (node0 + NPB > NN) ? NN : node0 + NPB;
  const int nnode = node1 - node0;
  if (t < NPB) hcnt[t] = 0;
  if (t < 64) h64[t] = 0;
  __syncthreads();

  const int gbase = b * CAP;
  const int gend = gcursor[b];   // after binA: b*CAP + bucket count
  const int cnt = gend - gbase;
  for (int i = gbase + t; i < gend; i += 256) {
    unsigned en = binned[i];
    lbin[i - gbase] = en;
    lrank[i - gbase] = (unsigned short)atomicAdd(&hcnt[en >> 17], 1);
  }
  __syncthreads();

  int v = (t < NPB) ? hcnt[t] : 0;
  if (t < NPB) sc[t] = v;
  __syncthreads();
#pragma unroll
  for (int o = 1; o < NPB; o <<= 1) {
    int add = (t < NPB && t >= o) ? sc[t - o] : 0;
    __syncthreads();
    if (t < NPB) sc[t] += add;
    __syncthreads();
  }
  if (t < NPB) {
    int rp = gbase + sc[t] - v;   // exclusive prefix within bucket
    lcur[t] = rp;                 // placement base (atomic-free)
    if (t < nnode) {
      rows[node0 + t] = make_int2(rp, rp + v);
      dinv[node0 + t] = rsqrtf((float)v + 1.0f);
    }
  }

  // ---- counting sort of the 128 local nodes by degree (invalid t -> deg 0) ----
  const int deg = (t < nnode) ? v : 0;
  const int dcl = deg > 63 ? 63 : deg;
  if (t < NPB) atomicAdd(&h64[dcl], 1);
  __syncthreads();
  int hv = (t < 64) ? h64[t] : 0;
  if (t < 64) s64[t] = hv;
  __syncthreads();
#pragma unroll
  for (int o = 1; o < 64; o <<= 1) {
    int add = (t < 64 && t >= o) ? s64[t - o] : 0;
    __syncthreads();
    if (t < 64) s64[t] += add;
    __syncthreads();
  }
  if (t < 64) h64[t] = s64[t] - hv;  // exclusive base -> cursor
  __syncthreads();
  if (t < NPB) {
    int p = atomicAdd(&h64[dcl], 1);
    sortOrd[b * NPB + p] = t;
  }
  __syncthreads();

  for (int i = t; i < cnt; i += 256) {
    unsigned en = lbin[i];
    col[lcur[en >> 17] + (int)lrank[i]] = (int)(en & 0x1FFFF);
  }
}

// ---------------- MFMA GEMM -> half-row layout, coalesced stores ----------------
// R8: all 8 nt tiles accumulate in registers; the wave's 16x128 bf16 tile is staged in
// per-wave LDS ([16][136] ushort, pad -> 2-way write / 4-way read conflicts only), then
// written out as uint4 (4x16B per lane into contiguous 128B half-rows). Replaces the
// 32 scalar 2B global stores per lane (1/8-line utilization) used in R0-R7.
// No __syncthreads: LDS tile is wave-local (last block has early-exit waves).
__global__ __launch_bounds__(256) void k_gemm_mfma(const float* __restrict__ X,
                                                   const unsigned short* __restrict__ Wt,
                                                   const float* __restrict__ dinv,
                                                   unsigned short* __restrict__ hs,
                                                   int nrows) {
  __shared__ unsigned short tile[4][16][136];
  const int wave = threadIdx.x >> 6;
  const int lane = threadIdx.x & 63;
  const int row0 = blockIdx.x * 64 + wave * 16;
  if (row0 >= nrows) return;
  const int lm = lane & 15;   // A-row / C-col
  const int lq = lane >> 4;   // quad

  int arow = row0 + lm;
  int arowc = arow < nrows ? arow : nrows - 1;  // clamp (stores are guarded)

  short8 afrag[4];
#pragma unroll
  for (int kc = 0; kc < 4; ++kc) {
    int k0 = kc * 32 + lq * 8;
    const float4* p = (const float4*)(X + (size_t)arowc * HD + k0);
    float4 f0 = p[0], f1 = p[1];
    short8 a;
    a[0] = (short)bf16_rne(f0.x); a[1] = (short)bf16_rne(f0.y);
    a[2] = (short)bf16_rne(f0.z); a[3] = (short)bf16_rne(f0.w);
    a[4] = (short)bf16_rne(f1.x); a[5] = (short)bf16_rne(f1.y);
    a[6] = (short)bf16_rne(f1.z); a[7] = (short)bf16_rne(f1.w);
    afrag[kc] = a;
  }

  float dv[4];
#pragma unroll
  for (int r = 0; r < 4; ++r) {
    int row = row0 + lq * 4 + r;
    dv[r] = dinv[row < nrows ? row : 0];
  }

  f32x4 accs[8];
#pragma unroll
  for (int nt = 0; nt < 8; ++nt) {
    f32x4 acc = {0.f, 0.f, 0.f, 0.f};
    const unsigned short* Wb = Wt + (size_t)(nt * 16 + lm) * HD + lq * 8;
#pragma unroll
    for (int kc = 0; kc < 4; ++kc) {
      short8 bfrag = *(const short8*)(Wb + kc * 32);
      acc = __builtin_amdgcn_mfma_f32_16x16x32_bf16(afrag[kc], bfrag, acc, 0, 0, 0);
    }
    accs[nt] = acc;
  }

  // stage the wave's 16x128 bf16 tile in LDS (scalar b16 writes, ~2-way conflicts)
#pragma unroll
  for (int nt = 0; nt < 8; ++nt)
#pragma unroll
    for (int r = 0; r < 4; ++r)
      tile[wave][lq * 4 + r][nt * 16 + lm] = bf16_rne(accs[nt][r] * dv[r]);

  // coalesced writeout: lane (lm, q): half = q>>1, chunk = q&1; 4 x 16B per lane
  const int half = lq >> 1;
  const int ch = lq & 1;
  const int row = row0 + lm;
  if (row < nrows) {
    unsigned short* dstp = hs + ((size_t)half * NN + row) * 64 + ch * 32;
#pragma unroll
    for (int j = 0; j < 4; ++j) {
      uint4 v = *(const uint4*)&tile[wave][lm][half * 64 + ch * 32 + j * 8];
      *(uint4*)(dstp + j * 8) = v;
    }
  }
}

// ---------------- half-row gather: 8 lanes per node, one full 128B line per edge ----------------
// Near random-access fetch floor: FETCH ~187MB at ~3.3TB/s (block->XCD not controllable;
// measured R5). Stratified degree-sorted positions keep waves degree-uniform.
__global__ __launch_bounds__(256) void k_gatherR(const uint4* __restrict__ hsv,
                                                 const float* __restrict__ dinv,
                                                 const int2* __restrict__ rows,
                                                 const int* __restrict__ col,
                                                 const int* __restrict__ sortOrd,
                                                 const float* __restrict__ b1,
                                                 const float* __restrict__ uv,
                                                 float2* __restrict__ qpart) {
  const int half = blockIdx.x & 1;     // feature half
  const int slice = (blockIdx.x >> 1) & 3;  // position slice
  const int g = blockIdx.x >> 3;       // bucket
  const int t = threadIdx.x;
  const int gi = t >> 3;               // group 0..31 (one node each)
  const int fl = t & 7;                // lane in group: local feats [fl*8, fl*8+8)
  const int p = gi * 4 + slice;        // stratified sorted position
  const int tloc = sortOrd[g * NPB + p];
  const int node = g * NPB + tloc;
  const bool valid = node < NN;

  int2 be = valid ? rows[node] : make_int2(0, 0);
  const uint4* plane = hsv + (size_t)half * NN * 8;

  float ax[8] = {0.f, 0.f, 0.f, 0.f, 0.f, 0.f, 0.f, 0.f};
  if (valid) acc_row8(ax, plane[(size_t)node * 8 + fl]);  // self term

  int e = be.x;
  const int eend = be.y;
  for (; e + 3 < eend; e += 4) {
    int c0 = col[e], c1 = col[e + 1], c2 = col[e + 2], c3 = col[e + 3];
    uint4 u0 = plane[(size_t)c0 * 8 + fl];
    uint4 u1 = plane[(size_t)c1 * 8 + fl];
    uint4 u2 = plane[(size_t)c2 * 8 + fl];
    uint4 u3 = plane[(size_t)c3 * 8 + fl];
    acc_row8(ax, u0); acc_row8(ax, u1); acc_row8(ax, u2); acc_row8(ax, u3);
  }
  for (; e < eend; ++e) acc_row8(ax, plane[(size_t)col[e] * 8 + fl]);

  // epilogue: relu + projection over own 8 feats, reduce across the 8-lane group
  float di = valid ? dinv[node] : 0.f;
  float s1 = 0.f, s2 = 0.f;
#pragma unroll
  for (int j = 0; j < 8; ++j) {
    int f = half * 64 + fl * 8 + j;
    float h = fmaxf(di * ax[j] + b1[f], 0.f);
    s1 += h * uv[f];
    s2 += h * uv[128 + f];
  }
#pragma unroll
  for (int o = 1; o < 8; o <<= 1) {
    s1 += __shfl_xor(s1, o);
    s2 += __shfl_xor(s2, o);
  }
  if (fl == 0 && valid) qpart[(size_t)half * NN + node] = make_float2(di * s1, di * s2);
}

// ---------------- qred: q[n] = qpart[0][n] + qpart[1][n] ----------------
__global__ void k_qred(const float2* __restrict__ qpart, float2* __restrict__ q, int n) {
  int i = blockIdx.x * 256 + threadIdx.x;
  if (i < n) {
    float2 a = qpart[i];
    float2 b = qpart[(size_t)NN + i];
    q[i] = make_float2(a.x + b.x, a.y + b.y);
  }
}

// ---------------- qagg: conv2+score collapsed (q table 800KB, L2-resident) ----------------
// Degree-sorted thread->node mapping (sortOrd) for wave-uniform inner-loop lengths.
#define LOADQ(P0, P1, P2, P3, pos)                                     \
  {                                                                    \
    P0 = q[col[(pos)]]; P1 = q[col[(pos) + 1]];                        \
    P2 = q[col[(pos) + 2]]; P3 = q[col[(pos) + 3]];                    \
  }
__global__ __launch_bounds__(256) void k_qagg(const float2* __restrict__ q,
                                              const float* __restrict__ dinv,
                                              const int2* __restrict__ rows,
                                              const int* __restrict__ col,
                                              const int* __restrict__ sortOrd,
                                              const float* __restrict__ uv,
                                              float2* __restrict__ sv) {
  const int idx = blockIdx.x * 256 + threadIdx.x;   // grid covers NB*NPB = 100096
  const int g = idx >> 7;
  const int node = g * NPB + sortOrd[idx];
  if (node >= NN) return;
  int2 be = rows[node];
  float2 a = q[node];
  float a1 = a.x, a2 = a.y;
  int e = be.x;
  const int eend = be.y;
  int n4 = (eend - e) >> 2;
  int ep = e;
  e += n4 << 2;
  if (n4) {
    float2 A0, A1, A2, A3, B0, B1, B2, B3;
    LOADQ(A0, A1, A2, A3, ep); ep += 4; n4--;
    while (n4 >= 2) {
      LOADQ(B0, B1, B2, B3, ep); ep += 4;
      a1 += (A0.x + A1.x) + (A2.x + A3.x);
      a2 += (A0.y + A1.y) + (A2.y + A3.y);
      LOADQ(A0, A1, A2, A3, ep); ep += 4;
      a1 += (B0.x + B1.x) + (B2.x + B3.x);
      a2 += (B0.y + B1.y) + (B2.y + B3.y);
      n4 -= 2;
    }
    if (n4) {
      LOADQ(B0, B1, B2, B3, ep);
      a1 += (A0.x + A1.x) + (A2.x + A3.x);
      a2 += (A0.y + A1.y) + (A2.y + A3.y);
      a1 += (B0.x + B1.x) + (B2.x + B3.x);
      a2 += (B0.y + B1.y) + (B2.y + B3.y);
    } else {
      a1 += (A0.x + A1.x) + (A2.x + A3.x);
      a2 += (A0.y + A1.y) + (A2.y + A3.y);
    }
  }
  for (; e < eend; ++e) {
    float2 qq = q[col[e]];
    a1 += qq.x; a2 += qq.y;
  }
  float di = dinv[node];
  sv[node] = make_float2(a1 * di + uv[256], a2 * di + uv[257]);
}

// ---------------- pair outputs: 2 pairs/thread, int2/float2 coalesced ----------------
__global__ void k_pairs(const float2* __restrict__ s, const int* __restrict__ I,
                        const int* __restrict__ J, const float* __restrict__ blin,
                        float* __restrict__ out, int np) {
  int p0 = (blockIdx.x * 256 + threadIdx.x) * 2;
  if (p0 + 1 < np) {
    int2 ii = *(const int2*)(I + p0);
    int2 jj = *(const int2*)(J + p0);
    float b = blin[0];
    float v0 = s[ii.x].x + s[jj.x].y + b;
    float v1 = s[ii.y].x + s[jj.y].y + b;
    *(float2*)(out + p0) = make_float2(1.f / (1.f + __expf(-v0)),
                                       1.f / (1.f + __expf(-v1)));
  } else if (p0 < np) {
    float v = s[I[p0]].x + s[J[p0]].y + blin[0];
    out[p0] = 1.f / (1.f + __expf(-v));
  }
}

extern "C" void kernel_launch(void* const* d_in, const int* in_sizes, int n_in,
                              void* d_out, int out_size, void* d_ws, size_t ws_size,
                              hipStream_t stream) {
  const float* x     = (const float*)d_in[0];
  const int*   eidx  = (const int*)d_in[1];
  const int*   Iidx  = (const int*)d_in[2];
  const int*   Jidx  = (const int*)d_in[3];
  const float* W1    = (const float*)d_in[4];
  const float* b1    = (const float*)d_in[5];
  const float* W2    = (const float*)d_in[6];
  const float* b2    = (const float*)d_in[7];
  const float* Wlin  = (const float*)d_in[8];
  const float* blin  = (const float*)d_in[9];
  const int* src = eidx;
  const int* dst = eidx + NE;

  // workspace layout: hs FIRST so half-rows are 128B-aligned (one line each)
  unsigned short* hs = (unsigned short*)d_ws;         // NN*HD bf16 = 25.6 MB (2 halves)
  float* dinv  = (float*)(hs + (size_t)NN * HD);      // 100000
  float* sv    = dinv + 100000;                       // 200000 (float2/node)
  float* qbuf  = sv + 200000;                         // 200000 (float2/node)
  float* qpart = qbuf + 200000;                       // 2*NN float2 = 400000
  float* uv    = qpart + 400000;                      // 264
  unsigned short* wt1 = (unsigned short*)(uv + 264);  // 16384 bf16
  int2* rows   = (int2*)(wt1 + 16384);                // NN int2 (8B-aligned)
  int* col     = (int*)(rows + NN);                   // NB*CAP = 2001920
  int* gcursor = col + NB * CAP;                      // NB (pad 784)
  int* sortOrd = gcursor + 784;                       // NB*NPB = 100096
  unsigned* binned = (unsigned*)(sortOrd + NB * NPB); // NB*CAP x 4B

  float* out = (float*)d_out;

  // ---- prep (weight prep + cursor init, fused) ----
  k_prep<<<66, 256, 0, stream>>>(W1, wt1, W2, Wlin, b2, uv, gcursor);

  // ---- CSR build (fixed-capacity buckets; rank-captured, single-atomic-pass) ----
  k_binA<<<NWG, 256, 0, stream>>>(src, dst, gcursor, binned, NE);
  k_binB<<<NB, 256, 0, stream>>>(binned, gcursor, rows, col, dinv, sortOrd);

  // conv1 GEMM -> half-row hs (coalesced stores)
  k_gemm_mfma<<<(NN + 63) / 64, 256, 0, stream>>>(x, wt1, dinv, hs, NN);

  // conv1 aggregation + relu + score projection (8 lanes/node, half-sharded)
  k_gatherR<<<NB * 8, 256, 0, stream>>>((const uint4*)hs, dinv, rows, col,
                                        sortOrd, b1, uv, (float2*)qpart);
  k_qred<<<(NN + 255) / 256, 256, 0, stream>>>((const float2*)qpart, (float2*)qbuf, NN);

  // conv2 + score head collapsed (degree-sorted)
  k_qagg<<<(NB * NPB) / 256, 256, 0, stream>>>((const float2*)qbuf, dinv, rows, col,
                                               sortOrd, uv, (float2*)sv);

  // pair outputs (2/thread)
  k_pairs<<<(NP / 2 + 255) / 256, 256, 0, stream>>>((const float2*)sv, Iidx, Jidx, blin, out, NP);
}

// Round 10
// 260.052 us; speedup vs baseline: 5.3050x; 1.0115x over previous
//
#include <hip/hip_runtime.h>
#include <hip/hip_bf16.h>
#include <math.h>

#define NN 100000
#define NE 1600000
#define NP 500000
#define HD 128
#define NPB 128                    // nodes per bucket (pow2)
#define NB 782                     // ceil(NN/NPB)
#define CAP 2560                   // bucket capacity (mean 2048, +11 sigma)
#define CHUNK 4096                 // edges per binning workgroup
#define NWG 391                    // ceil(NE/CHUNK)
#define GEMMB 1563                 // gemm blocks in fused kernel = ceil(NN/64)

typedef __attribute__((ext_vector_type(8))) short short8;   // 8 bf16 = 4 VGPRs
typedef __attribute__((ext_vector_type(4))) float f32x4;

// ---- bf16 helpers ----
__device__ __forceinline__ float bf_lo(unsigned int u) { return __uint_as_float(u << 16); }
__device__ __forceinline__ float bf_hi(unsigned int u) { return __uint_as_float(u & 0xffff0000u); }
__device__ __forceinline__ unsigned short bf16_rne(float f) {
  unsigned int u = __float_as_uint(f);
  u = (u + 0x7fffu + ((u >> 16) & 1u)) >> 16;
  return (unsigned short)u;
}
// ax[j] += s * bf16[j]  (FMA — same VALU cost as plain add)
__device__ __forceinline__ void acc_row8s(float* ax, uint4 u, float s) {
  ax[0] = fmaf(s, bf_lo(u.x), ax[0]); ax[1] = fmaf(s, bf_hi(u.x), ax[1]);
  ax[2] = fmaf(s, bf_lo(u.y), ax[2]); ax[3] = fmaf(s, bf_hi(u.y), ax[3]);
  ax[4] = fmaf(s, bf_lo(u.z), ax[4]); ax[5] = fmaf(s, bf_hi(u.z), ax[5]);
  ax[6] = fmaf(s, bf_lo(u.w), ax[6]); ax[7] = fmaf(s, bf_hi(u.w), ax[7]);
}

// ---------------- prep (fused): W1 transpose/cast + u-vectors + gcursor init ----------------
__global__ __launch_bounds__(256) void k_prep(const float* __restrict__ W1,
                                              unsigned short* __restrict__ Wt,
                                              const float* __restrict__ W2,
                                              const float* __restrict__ Wl,
                                              const float* __restrict__ b2,
                                              float* __restrict__ uv,
                                              int* __restrict__ gcursor) {
  const int blk = blockIdx.x;
  const int t = threadIdx.x;
  if (blk < 64) {
    int i = blk * 256 + t;           // 16384
    int n = i >> 7, k = i & 127;
    Wt[i] = bf16_rne(W1[k * HD + n]);
  } else if (blk == 64) {
    // u-vectors: u1 = W2@Wl[:128], u2 = W2@Wl[128:], c1/c2 = b2.Wl
    __shared__ float sh[256];
    const int half = t >> 7;
    const int k = t & 127;
    const float* wl = Wl + half * 128;
    float s = 0.f;
    for (int c = 0; c < 128; ++c) s += W2[k * HD + c] * wl[c];
    uv[half * 128 + k] = s;

    sh[t] = b2[k] * Wl[half * 128 + k];
    __syncthreads();
    for (int o = 64; o > 0; o >>= 1) {
      if ((t & 127) < o) sh[t] += sh[t + o];
      __syncthreads();
    }
    if (t == 0) uv[256] = sh[0];
    if (t == 128) uv[257] = sh[128];
  } else {
    for (int i = t; i < NB; i += 256) gcursor[i] = i * CAP;
  }
}

// ---------------- fused: GEMM (blocks 0..GEMMB-1) || binA (blocks GEMMB..GEMMB+NWG-1) ----
// R9: hs stores UNSCALED h (dinv applied per-edge in gatherR), removing gemm's dependency
// on binB -> gemm and binA are independent and run concurrently in one dispatch.
// LDS union: gemm tile 17408B / binA hist+base 6256B -> 8 blocks/CU, all 1954 co-resident.
__global__ __launch_bounds__(256) void k_fusedAG(const float* __restrict__ X,
                                                 const unsigned short* __restrict__ Wt,
                                                 unsigned short* __restrict__ hs,
                                                 const int* __restrict__ src,
                                                 const int* __restrict__ dst,
                                                 int* __restrict__ gcursor,
                                                 unsigned* __restrict__ binned) {
  __shared__ __align__(16) unsigned char smem[17408];
  const int t = threadIdx.x;

  if (blockIdx.x < GEMMB) {
    // ================= GEMM role =================
    unsigned short (*tile)[16][136] = (unsigned short (*)[16][136])smem;
    const int wave = t >> 6;
    const int lane = t & 63;
    const int row0 = blockIdx.x * 64 + wave * 16;
    if (row0 >= NN) return;
    const int lm = lane & 15;   // A-row / C-col
    const int lq = lane >> 4;   // quad

    int arow = row0 + lm;
    int arowc = arow < NN ? arow : NN - 1;  // clamp (stores are guarded)

    short8 afrag[4];
#pragma unroll
    for (int kc = 0; kc < 4; ++kc) {
      int k0 = kc * 32 + lq * 8;
      const float4* p = (const float4*)(X + (size_t)arowc * HD + k0);
      float4 f0 = p[0], f1 = p[1];
      short8 a;
      a[0] = (short)bf16_rne(f0.x); a[1] = (short)bf16_rne(f0.y);
      a[2] = (short)bf16_rne(f0.z); a[3] = (short)bf16_rne(f0.w);
      a[4] = (short)bf16_rne(f1.x); a[5] = (short)bf16_rne(f1.y);
      a[6] = (short)bf16_rne(f1.z); a[7] = (short)bf16_rne(f1.w);
      afrag[kc] = a;
    }

    f32x4 accs[8];
#pragma unroll
    for (int nt = 0; nt < 8; ++nt) {
      f32x4 acc = {0.f, 0.f, 0.f, 0.f};
      const unsigned short* Wb = Wt + (size_t)(nt * 16 + lm) * HD + lq * 8;
#pragma unroll
      for (int kc = 0; kc < 4; ++kc) {
        short8 bfrag = *(const short8*)(Wb + kc * 32);
        acc = __builtin_amdgcn_mfma_f32_16x16x32_bf16(afrag[kc], bfrag, acc, 0, 0, 0);
      }
      accs[nt] = acc;
    }

    // stage the wave's 16x128 bf16 tile in LDS (unscaled h)
#pragma unroll
    for (int nt = 0; nt < 8; ++nt)
#pragma unroll
      for (int r = 0; r < 4; ++r)
        tile[wave][lq * 4 + r][nt * 16 + lm] = bf16_rne(accs[nt][r]);

    // coalesced writeout: lane (lm, q): half = q>>1, chunk = q&1; 4 x 16B per lane
    const int half = lq >> 1;
    const int ch = lq & 1;
    const int row = row0 + lm;
    if (row < NN) {
      unsigned short* dstp = hs + ((size_t)half * NN + row) * 64 + ch * 32;
#pragma unroll
      for (int j = 0; j < 4; ++j) {
        uint4 v = *(const uint4*)&tile[wave][lm][half * 64 + ch * 32 + j * 8];
        *(uint4*)(dstp + j * 8) = v;
      }
    }
  } else {
    // ================= binA role =================
    int* hist = (int*)smem;            // NB ints
    int* base = hist + NB;             // NB ints (total 6256B <= 17408)
    const int e0 = (blockIdx.x - GEMMB) * CHUNK;

    for (int i = t; i < NB; i += 256) hist[i] = 0;
    __syncthreads();

    int dstv[CHUNK / 256];
    int rank[CHUNK / 256];
#pragma unroll
    for (int k = 0; k < CHUNK / 256; ++k) {
      int e = e0 + k * 256 + t;
      dstv[k] = (e < NE) ? dst[e] : -1;
      rank[k] = (dstv[k] >= 0) ? atomicAdd(&hist[dstv[k] >> 7], 1) : 0;
    }
    __syncthreads();

    for (int i = t; i < NB; i += 256) {
      int c = hist[i];
      base[i] = c ? atomicAdd(&gcursor[i], c) : 0;
    }
    __syncthreads();

#pragma unroll
    for (int k = 0; k < CHUNK / 256; ++k) {
      int d = dstv[k];
      if (d >= 0) {
        int e = e0 + k * 256 + t;
        int pos = base[d >> 7] + rank[k];
        binned[pos] = (unsigned)src[e] | ((unsigned)(d & 127) << 17);
      }
    }
  }
}

// ---- binB: per-node count -> rows + dinv + degree-sorted order, then CSR placement ----
// Entries + per-entry ranks staged in LDS during the count pass; placement is atomic-free.
__global__ __launch_bounds__(256) void k_binB(const unsigned* __restrict__ binned,
                                              const int* __restrict__ gcursor,
                                              int2* __restrict__ rows,
                                              int* __restrict__ col,
                                              float* __restrict__ dinv,
                                              int* __restrict__ sortOrd) {
  __shared__ unsigned lbin[CAP];
  __shared__ unsigned short lrank[CAP];
  __shared__ int hcnt[NPB];
  __shared__ int sc[NPB];
  __shared__ int lcur[NPB];
  __shared__ int h64[64];
  __shared__ int s64[64];
  const int b = blockIdx.x;
  const int t = threadIdx.x;
  const int node0 = b * NPB;
  const int node1 = (node0 + NPB > NN) ? NN : node0 + NPB;
  const int nnode = node1 - node0;
  if (t < NPB) hcnt[t] = 0;
  if (t < 64) h64[t] = 0;
  __syncthreads();

  const int gbase = b * CAP;
  const int gend = gcursor[b];   // after binA: b*CAP + bucket count
  const int cnt = gend - gbase;
  for (int i = gbase + t; i < gend; i += 256) {
    unsigned en = binned[i];
    lbin[i - gbase] = en;
    lrank[i - gbase] = (unsigned short)atomicAdd(&hcnt[en >> 17], 1);
  }
  __syncthreads();

  int v = (t < NPB) ? hcnt[t] : 0;
  if (t < NPB) sc[t] = v;
  __syncthreads();
#pragma unroll
  for (int o = 1; o < NPB; o <<= 1) {
    int add = (t < NPB && t >= o) ? sc[t - o] : 0;
    __syncthreads();
    if (t < NPB) sc[t] += add;
    __syncthreads();
  }
  if (t < NPB) {
    int rp = gbase + sc[t] - v;   // exclusive prefix within bucket
    lcur[t] = rp;                 // placement base (atomic-free)
    if (t < nnode) {
      rows[node0 + t] = make_int2(rp, rp + v);
      dinv[node0 + t] = rsqrtf((float)v + 1.0f);
    }
  }

  // ---- counting sort of the 128 local nodes by degree (invalid t -> deg 0) ----
  const int deg = (t < nnode) ? v : 0;
  const int dcl = deg > 63 ? 63 : deg;
  if (t < NPB) atomicAdd(&h64[dcl], 1);
  __syncthreads();
  int hv = (t < 64) ? h64[t] : 0;
  if (t < 64) s64[t] = hv;
  __syncthreads();
#pragma unroll
  for (int o = 1; o < 64; o <<= 1) {
    int add = (t < 64 && t >= o) ? s64[t - o] : 0;
    __syncthreads();
    if (t < 64) s64[t] += add;
    __syncthreads();
  }
  if (t < 64) h64[t] = s64[t] - hv;  // exclusive base -> cursor
  __syncthreads();
  if (t < NPB) {
    int p = atomicAdd(&h64[dcl], 1);
    sortOrd[b * NPB + p] = t;
  }
  __syncthreads();

  for (int i = t; i < cnt; i += 256) {
    unsigned en = lbin[i];
    col[lcur[en >> 17] + (int)lrank[i]] = (int)(en & 0x1FFFF);
  }
}

// ---------------- half-row gather: 8 lanes per node, one full 128B line per edge ----------------
// hs unscaled: apply dinv[src] per edge (broadcast 4B L2 load; table 400KB resident).
// acc becomes FMA (same VALU cost). Stratified degree-sorted positions keep waves uniform.
__global__ __launch_bounds__(256) void k_gatherR(const uint4* __restrict__ hsv,
                                                 const float* __restrict__ dinv,
                                                 const int2* __restrict__ rows,
                                                 const int* __restrict__ col,
                                                 const int* __restrict__ sortOrd,
                                                 const float* __restrict__ b1,
                                                 const float* __restrict__ uv,
                                                 float2* __restrict__ qpart) {
  const int half = blockIdx.x & 1;     // feature half
  const int slice = (blockIdx.x >> 1) & 3;  // position slice
  const int g = blockIdx.x >> 3;       // bucket
  const int t = threadIdx.x;
  const int gi = t >> 3;               // group 0..31 (one node each)
  const int fl = t & 7;                // lane in group: local feats [fl*8, fl*8+8)
  const int p = gi * 4 + slice;        // stratified sorted position
  const int tloc = sortOrd[g * NPB + p];
  const int node = g * NPB + tloc;
  const bool valid = node < NN;

  int2 be = valid ? rows[node] : make_int2(0, 0);
  const uint4* plane = hsv + (size_t)half * NN * 8;
  const float di = valid ? dinv[node] : 0.f;

  float ax[8] = {0.f, 0.f, 0.f, 0.f, 0.f, 0.f, 0.f, 0.f};
  if (valid) acc_row8s(ax, plane[(size_t)node * 8 + fl], di);  // self: di*h[n]

  int e = be.x;
  const int eend = be.y;
  for (; e + 3 < eend; e += 4) {
    int c0 = col[e], c1 = col[e + 1], c2 = col[e + 2], c3 = col[e + 3];
    uint4 u0 = plane[(size_t)c0 * 8 + fl];
    uint4 u1 = plane[(size_t)c1 * 8 + fl];
    uint4 u2 = plane[(size_t)c2 * 8 + fl];
    uint4 u3 = plane[(size_t)c3 * 8 + fl];
    float w0 = dinv[c0], w1 = dinv[c1], w2 = dinv[c2], w3 = dinv[c3];
    acc_row8s(ax, u0, w0); acc_row8s(ax, u1, w1);
    acc_row8s(ax, u2, w2); acc_row8s(ax, u3, w3);
  }
  for (; e < eend; ++e) {
    int c = col[e];
    acc_row8s(ax, plane[(size_t)c * 8 + fl], dinv[c]);
  }

  // epilogue: relu + projection over own 8 feats, reduce across the 8-lane group
  float s1 = 0.f, s2 = 0.f;
#pragma unroll
  for (int j = 0; j < 8; ++j) {
    int f = half * 64 + fl * 8 + j;
    float h = fmaxf(di * ax[j] + b1[f], 0.f);
    s1 += h * uv[f];
    s2 += h * uv[128 + f];
  }
#pragma unroll
  for (int o = 1; o < 8; o <<= 1) {
    s1 += __shfl_xor(s1, o);
    s2 += __shfl_xor(s2, o);
  }
  if (fl == 0 && valid) qpart[(size_t)half * NN + node] = make_float2(di * s1, di * s2);
}

// ---------------- qred: q[n] = qpart[0][n] + qpart[1][n] ----------------
__global__ void k_qred(const float2* __restrict__ qpart, float2* __restrict__ q, int n) {
  int i = blockIdx.x * 256 + threadIdx.x;
  if (i < n) {
    float2 a = qpart[i];
    float2 b = qpart[(size_t)NN + i];
    q[i] = make_float2(a.x + b.x, a.y + b.y);
  }
}

// ---------------- qagg: conv2+score collapsed (q table 800KB, L2-resident) ----------------
// Degree-sorted thread->node mapping (sortOrd) for wave-uniform inner-loop lengths.
#define LOADQ(P0, P1, P2, P3, pos)                                     \
  {                                                                    \
    P0 = q[col[(pos)]]; P1 = q[col[(pos) + 1]];                        \
    P2 = q[col[(pos) + 2]]; P3 = q[col[(pos) + 3]];                    \
  }
__global__ __launch_bounds__(256) void k_qagg(const float2* __restrict__ q,
                                              const float* __restrict__ dinv,
                                              const int2* __restrict__ rows,
                                              const int* __restrict__ col,
                                              const int* __restrict__ sortOrd,
                                              const float* __restrict__ uv,
                                              float2* __restrict__ sv) {
  const int idx = blockIdx.x * 256 + threadIdx.x;   // grid covers NB*NPB = 100096
  const int g = idx >> 7;
  const int node = g * NPB + sortOrd[idx];
  if (node >= NN) return;
  int2 be = rows[node];
  float2 a = q[node];
  float a1 = a.x, a2 = a.y;
  int e = be.x;
  const int eend = be.y;
  int n4 = (eend - e) >> 2;
  int ep = e;
  e += n4 << 2;
  if (n4) {
    float2 A0, A1, A2, A3, B0, B1, B2, B3;
    LOADQ(A0, A1, A2, A3, ep); ep += 4; n4--;
    while (n4 >= 2) {
      LOADQ(B0, B1, B2, B3, ep); ep += 4;
      a1 += (A0.x + A1.x) + (A2.x + A3.x);
      a2 += (A0.y + A1.y) + (A2.y + A3.y);
      LOADQ(A0, A1, A2, A3, ep); ep += 4;
      a1 += (B0.x + B1.x) + (B2.x + B3.x);
      a2 += (B0.y + B1.y) + (B2.y + B3.y);
      n4 -= 2;
    }
    if (n4) {
      LOADQ(B0, B1, B2, B3, ep);
      a1 += (A0.x + A1.x) + (A2.x + A3.x);
      a2 += (A0.y + A1.y) + (A2.y + A3.y);
      a1 += (B0.x + B1.x) + (B2.x + B3.x);
      a2 += (B0.y + B1.y) + (B2.y + B3.y);
    } else {
      a1 += (A0.x + A1.x) + (A2.x + A3.x);
      a2 += (A0.y + A1.y) + (A2.y + A3.y);
    }
  }
  for (; e < eend; ++e) {
    float2 qq = q[col[e]];
    a1 += qq.x; a2 += qq.y;
  }
  float di = dinv[node];
  sv[node] = make_float2(a1 * di + uv[256], a2 * di + uv[257]);
}

// ---------------- pair outputs: 2 pairs/thread, int2/float2 coalesced ----------------
__global__ void k_pairs(const float2* __restrict__ s, const int* __restrict__ I,
                        const int* __restrict__ J, const float* __restrict__ blin,
                        float* __restrict__ out, int np) {
  int p0 = (blockIdx.x * 256 + threadIdx.x) * 2;
  if (p0 + 1 < np) {
    int2 ii = *(const int2*)(I + p0);
    int2 jj = *(const int2*)(J + p0);
    float b = blin[0];
    float v0 = s[ii.x].x + s[jj.x].y + b;
    float v1 = s[ii.y].x + s[jj.y].y + b;
    *(float2*)(out + p0) = make_float2(1.f / (1.f + __expf(-v0)),
                                       1.f / (1.f + __expf(-v1)));
  } else if (p0 < np) {
    float v = s[I[p0]].x + s[J[p0]].y + blin[0];
    out[p0] = 1.f / (1.f + __expf(-v));
  }
}

extern "C" void kernel_launch(void* const* d_in, const int* in_sizes, int n_in,
                              void* d_out, int out_size, void* d_ws, size_t ws_size,
                              hipStream_t stream) {
  const float* x     = (const float*)d_in[0];
  const int*   eidx  = (const int*)d_in[1];
  const int*   Iidx  = (const int*)d_in[2];
  const int*   Jidx  = (const int*)d_in[3];
  const float* W1    = (const float*)d_in[4];
  const float* b1    = (const float*)d_in[5];
  const float* W2    = (const float*)d_in[6];
  const float* b2    = (const float*)d_in[7];
  const float* Wlin  = (const float*)d_in[8];
  const float* blin  = (const float*)d_in[9];
  const int* src = eidx;
  const int* dst = eidx + NE;

  // workspace layout: hs FIRST so half-rows are 128B-aligned (one line each)
  unsigned short* hs = (unsigned short*)d_ws;         // NN*HD bf16 = 25.6 MB (2 halves)
  float* dinv  = (float*)(hs + (size_t)NN * HD);      // 100000
  float* sv    = dinv + 100000;                       // 200000 (float2/node)
  float* qbuf  = sv + 200000;                         // 200000 (float2/node)
  float* qpart = qbuf + 200000;                       // 2*NN float2 = 400000
  float* uv    = qpart + 400000;                      // 264
  unsigned short* wt1 = (unsigned short*)(uv + 264);  // 16384 bf16
  int2* rows   = (int2*)(wt1 + 16384);                // NN int2 (8B-aligned)
  int* col     = (int*)(rows + NN);                   // NB*CAP = 2001920
  int* gcursor = col + NB * CAP;                      // NB (pad 784)
  int* sortOrd = gcursor + 784;                       // NB*NPB = 100096
  unsigned* binned = (unsigned*)(sortOrd + NB * NPB); // NB*CAP x 4B

  float* out = (float*)d_out;

  // ---- prep (weight prep + cursor init, fused) ----
  k_prep<<<66, 256, 0, stream>>>(W1, wt1, W2, Wlin, b2, uv, gcursor);

  // ---- GEMM (unscaled) || binA, one dispatch (independent after prep) ----
  k_fusedAG<<<GEMMB + NWG, 256, 0, stream>>>(x, wt1, hs, src, dst, gcursor, binned);

  // ---- binB: rows/col/dinv/sortOrd ----
  k_binB<<<NB, 256, 0, stream>>>(binned, gcursor, rows, col, dinv, sortOrd);

  // conv1 aggregation + relu + score projection (8 lanes/node, per-edge dinv[src])
  k_gatherR<<<NB * 8, 256, 0, stream>>>((const uint4*)hs, dinv, rows, col,
                                        sortOrd, b1, uv, (float2*)qpart);
  k_qred<<<(NN + 255) / 256, 256, 0, stream>>>((const float2*)qpart, (float2*)qbuf, NN);

  // conv2 + score head collapsed (degree-sorted)
  k_qagg<<<(NB * NPB) / 256, 256, 0, stream>>>((const float2*)qbuf, dinv, rows, col,
                                               sortOrd, uv, (float2*)sv);

  // pair outputs (2/thread)
  k_pairs<<<(NP / 2 + 255) / 256, 256, 0, stream>>>((const float2*)sv, Iidx, Jidx, blin, out, NP);
}

// Round 11
// 257.108 us; speedup vs baseline: 5.3657x; 1.0114x over previous
//
#include <hip/hip_runtime.h>
#include <hip/hip_bf16.h>
#include <math.h>

#define NN 100000
#define NE 1600000
#define NP 500000
#define HD 128
#define NPB 128                    // nodes per bucket (pow2)
#define NB 782                     // ceil(NN/NPB)
#define CAP 2560                   // bucket capacity (mean 2048, +11 sigma)
#define CHUNK 4096                 // edges per binning workgroup
#define NWG 391                    // ceil(NE/CHUNK)
#define GEMMB 1563                 // gemm blocks in fused kernel = ceil(NN/64)

typedef __attribute__((ext_vector_type(8))) short short8;   // 8 bf16 = 4 VGPRs
typedef __attribute__((ext_vector_type(4))) float f32x4;

// ---- bf16 helpers ----
__device__ __forceinline__ float bf_lo(unsigned int u) { return __uint_as_float(u << 16); }
__device__ __forceinline__ float bf_hi(unsigned int u) { return __uint_as_float(u & 0xffff0000u); }
__device__ __forceinline__ unsigned short bf16_rne(float f) {
  unsigned int u = __float_as_uint(f);
  u = (u + 0x7fffu + ((u >> 16) & 1u)) >> 16;
  return (unsigned short)u;
}
// ax[j] += s * bf16[j]  (FMA — same VALU cost as plain add)
__device__ __forceinline__ void acc_row8s(float* ax, uint4 u, float s) {
  ax[0] = fmaf(s, bf_lo(u.x), ax[0]); ax[1] = fmaf(s, bf_hi(u.x), ax[1]);
  ax[2] = fmaf(s, bf_lo(u.y), ax[2]); ax[3] = fmaf(s, bf_hi(u.y), ax[3]);
  ax[4] = fmaf(s, bf_lo(u.z), ax[4]); ax[5] = fmaf(s, bf_hi(u.z), ax[5]);
  ax[6] = fmaf(s, bf_lo(u.w), ax[6]); ax[7] = fmaf(s, bf_hi(u.w), ax[7]);
}

// ---------------- prep (fused): W1 transpose/cast + u-vectors + gcursor init ----------------
__global__ __launch_bounds__(256) void k_prep(const float* __restrict__ W1,
                                              unsigned short* __restrict__ Wt,
                                              const float* __restrict__ W2,
                                              const float* __restrict__ Wl,
                                              const float* __restrict__ b2,
                                              float* __restrict__ uv,
                                              int* __restrict__ gcursor) {
  const int blk = blockIdx.x;
  const int t = threadIdx.x;
  if (blk < 64) {
    int i = blk * 256 + t;           // 16384
    int n = i >> 7, k = i & 127;
    Wt[i] = bf16_rne(W1[k * HD + n]);
  } else if (blk == 64) {
    // u-vectors: u1 = W2@Wl[:128], u2 = W2@Wl[128:], c1/c2 = b2.Wl
    __shared__ float sh[256];
    const int half = t >> 7;
    const int k = t & 127;
    const float* wl = Wl + half * 128;
    float s = 0.f;
    for (int c = 0; c < 128; ++c) s += W2[k * HD + c] * wl[c];
    uv[half * 128 + k] = s;

    sh[t] = b2[k] * Wl[half * 128 + k];
    __syncthreads();
    for (int o = 64; o > 0; o >>= 1) {
      if ((t & 127) < o) sh[t] += sh[t + o];
      __syncthreads();
    }
    if (t == 0) uv[256] = sh[0];
    if (t == 128) uv[257] = sh[128];
  } else {
    for (int i = t; i < NB; i += 256) gcursor[i] = i * CAP;
  }
}

// ---------------- fused: GEMM || binA, roles INTERLEAVED by blockIdx ----------------
// R11: R10 showed fused time == sum of parts (no overlap) with binA blocks at the grid
// tail: blocks are consumed ~in dispatch order, so the two roles ran back-to-back.
// Stripe the roles: binA on every 5th block (g%5==0, 391 total), gemm on the rest (1563).
// Both populations now co-resident from t=0; gemm's idle pipes hide binA's latency.
__global__ __launch_bounds__(256) void k_fusedAG(const float* __restrict__ X,
                                                 const unsigned short* __restrict__ Wt,
                                                 unsigned short* __restrict__ hs,
                                                 const int* __restrict__ src,
                                                 const int* __restrict__ dst,
                                                 int* __restrict__ gcursor,
                                                 unsigned* __restrict__ binned) {
  __shared__ __align__(16) unsigned char smem[17408];
  const int t = threadIdx.x;
  const int g = blockIdx.x;
  const bool isBin = (g % 5 == 0);   // 391 binA blocks: g = 0,5,...,1950

  if (!isBin) {
    // ================= GEMM role =================
    const int gemmId = g - g / 5 - 1;   // 0..1562 (dense over g%5!=0)
    unsigned short (*tile)[16][136] = (unsigned short (*)[16][136])smem;
    const int wave = t >> 6;
    const int lane = t & 63;
    const int row0 = gemmId * 64 + wave * 16;
    if (row0 >= NN) return;
    const int lm = lane & 15;   // A-row / C-col
    const int lq = lane >> 4;   // quad

    int arow = row0 + lm;
    int arowc = arow < NN ? arow : NN - 1;  // clamp (stores are guarded)

    short8 afrag[4];
#pragma unroll
    for (int kc = 0; kc < 4; ++kc) {
      int k0 = kc * 32 + lq * 8;
      const float4* p = (const float4*)(X + (size_t)arowc * HD + k0);
      float4 f0 = p[0], f1 = p[1];
      short8 a;
      a[0] = (short)bf16_rne(f0.x); a[1] = (short)bf16_rne(f0.y);
      a[2] = (short)bf16_rne(f0.z); a[3] = (short)bf16_rne(f0.w);
      a[4] = (short)bf16_rne(f1.x); a[5] = (short)bf16_rne(f1.y);
      a[6] = (short)bf16_rne(f1.z); a[7] = (short)bf16_rne(f1.w);
      afrag[kc] = a;
    }

    f32x4 accs[8];
#pragma unroll
    for (int nt = 0; nt < 8; ++nt) {
      f32x4 acc = {0.f, 0.f, 0.f, 0.f};
      const unsigned short* Wb = Wt + (size_t)(nt * 16 + lm) * HD + lq * 8;
#pragma unroll
      for (int kc = 0; kc < 4; ++kc) {
        short8 bfrag = *(const short8*)(Wb + kc * 32);
        acc = __builtin_amdgcn_mfma_f32_16x16x32_bf16(afrag[kc], bfrag, acc, 0, 0, 0);
      }
      accs[nt] = acc;
    }

    // stage the wave's 16x128 bf16 tile in LDS (unscaled h)
#pragma unroll
    for (int nt = 0; nt < 8; ++nt)
#pragma unroll
      for (int r = 0; r < 4; ++r)
        tile[wave][lq * 4 + r][nt * 16 + lm] = bf16_rne(accs[nt][r]);

    // coalesced writeout: lane (lm, q): half = q>>1, chunk = q&1; 4 x 16B per lane
    const int half = lq >> 1;
    const int ch = lq & 1;
    const int row = row0 + lm;
    if (row < NN) {
      unsigned short* dstp = hs + ((size_t)half * NN + row) * 64 + ch * 32;
#pragma unroll
      for (int j = 0; j < 4; ++j) {
        uint4 v = *(const uint4*)&tile[wave][lm][half * 64 + ch * 32 + j * 8];
        *(uint4*)(dstp + j * 8) = v;
      }
    }
  } else {
    // ================= binA role =================
    const int chunkId = g / 5;         // 0..390
    int* hist = (int*)smem;            // NB ints
    int* base = hist + NB;             // NB ints (total 6256B <= 17408)
    const int e0 = chunkId * CHUNK;

    for (int i = t; i < NB; i += 256) hist[i] = 0;
    __syncthreads();

    int dstv[CHUNK / 256];
    int rank[CHUNK / 256];
#pragma unroll
    for (int k = 0; k < CHUNK / 256; ++k) {
      int e = e0 + k * 256 + t;
      dstv[k] = (e < NE) ? dst[e] : -1;
      rank[k] = (dstv[k] >= 0) ? atomicAdd(&hist[dstv[k] >> 7], 1) : 0;
    }
    __syncthreads();

    for (int i = t; i < NB; i += 256) {
      int c = hist[i];
      base[i] = c ? atomicAdd(&gcursor[i], c) : 0;
    }
    __syncthreads();

#pragma unroll
    for (int k = 0; k < CHUNK / 256; ++k) {
      int d = dstv[k];
      if (d >= 0) {
        int e = e0 + k * 256 + t;
        int pos = base[d >> 7] + rank[k];
        binned[pos] = (unsigned)src[e] | ((unsigned)(d & 127) << 17);
      }
    }
  }
}

// ---- binB: per-node count -> rows + dinv + degree-sorted order, then CSR placement ----
// Entries + per-entry ranks staged in LDS during the count pass; placement is atomic-free.
__global__ __launch_bounds__(256) void k_binB(const unsigned* __restrict__ binned,
                                              const int* __restrict__ gcursor,
                                              int2* __restrict__ rows,
                                              int* __restrict__ col,
                                              float* __restrict__ dinv,
                                              int* __restrict__ sortOrd) {
  __shared__ unsigned lbin[CAP];
  __shared__ unsigned short lrank[CAP];
  __shared__ int hcnt[NPB];
  __shared__ int sc[NPB];
  __shared__ int lcur[NPB];
  __shared__ int h64[64];
  __shared__ int s64[64];
  const int b = blockIdx.x;
  const int t = threadIdx.x;
  const int node0 = b * NPB;
  const int node1 = (node0 + NPB > NN) ? NN : node0 + NPB;
  const int nnode = node1 - node0;
  if (t < NPB) hcnt[t] = 0;
  if (t < 64) h64[t] = 0;
  __syncthreads();

  const int gbase = b * CAP;
  const int gend = gcursor[b];   // after binA: b*CAP + bucket count
  const int cnt = gend - gbase;
  for (int i = gbase + t; i < gend; i += 256) {
    unsigned en = binned[i];
    lbin[i - gbase] = en;
    lrank[i - gbase] = (unsigned short)atomicAdd(&hcnt[en >> 17], 1);
  }
  __syncthreads();

  int v = (t < NPB) ? hcnt[t] : 0;
  if (t < NPB) sc[t] = v;
  __syncthreads();
#pragma unroll
  for (int o = 1; o < NPB; o <<= 1) {
    int add = (t < NPB && t >= o) ? sc[t - o] : 0;
    __syncthreads();
    if (t < NPB) sc[t] += add;
    __syncthreads();
  }
  if (t < NPB) {
    int rp = gbase + sc[t] - v;   // exclusive prefix within bucket
    lcur[t] = rp;                 // placement base (atomic-free)
    if (t < nnode) {
      rows[node0 + t] = make_int2(rp, rp + v);
      dinv[node0 + t] = rsqrtf((float)v + 1.0f);
    }
  }

  // ---- counting sort of the 128 local nodes by degree (invalid t -> deg 0) ----
  const int deg = (t < nnode) ? v : 0;
  const int dcl = deg > 63 ? 63 : deg;
  if (t < NPB) atomicAdd(&h64[dcl], 1);
  __syncthreads();
  int hv = (t < 64) ? h64[t] : 0;
  if (t < 64) s64[t] = hv;
  __syncthreads();
#pragma unroll
  for (int o = 1; o < 64; o <<= 1) {
    int add = (t < 64 && t >= o) ? s64[t - o] : 0;
    __syncthreads();
    if (t < 64) s64[t] += add;
    __syncthreads();
  }
  if (t < 64) h64[t] = s64[t] - hv;  // exclusive base -> cursor
  __syncthreads();
  if (t < NPB) {
    int p = atomicAdd(&h64[dcl], 1);
    sortOrd[b * NPB + p] = t;
  }
  __syncthreads();

  for (int i = t; i < cnt; i += 256) {
    unsigned en = lbin[i];
    col[lcur[en >> 17] + (int)lrank[i]] = (int)(en & 0x1FFFF);
  }
}

// ---------------- half-row gather: 8 lanes per node, one full 128B line per edge ----------------
// hs unscaled: apply dinv[src] per edge (broadcast 4B L2 load; table 400KB resident).
// acc becomes FMA (same VALU cost). Stratified degree-sorted positions keep waves uniform.
__global__ __launch_bounds__(256) void k_gatherR(const uint4* __restrict__ hsv,
                                                 const float* __restrict__ dinv,
                                                 const int2* __restrict__ rows,
                                                 const int* __restrict__ col,
                                                 const int* __restrict__ sortOrd,
                                                 const float* __restrict__ b1,
                                                 const float* __restrict__ uv,
                                                 float2* __restrict__ qpart) {
  const int half = blockIdx.x & 1;     // feature half
  const int slice = (blockIdx.x >> 1) & 3;  // position slice
  const int g = blockIdx.x >> 3;       // bucket
  const int t = threadIdx.x;
  const int gi = t >> 3;               // group 0..31 (one node each)
  const int fl = t & 7;                // lane in group: local feats [fl*8, fl*8+8)
  const int p = gi * 4 + slice;        // stratified sorted position
  const int tloc = sortOrd[g * NPB + p];
  const int node = g * NPB + tloc;
  const bool valid = node < NN;

  int2 be = valid ? rows[node] : make_int2(0, 0);
  const uint4* plane = hsv + (size_t)half * NN * 8;
  const float di = valid ? dinv[node] : 0.f;

  float ax[8] = {0.f, 0.f, 0.f, 0.f, 0.f, 0.f, 0.f, 0.f};
  if (valid) acc_row8s(ax, plane[(size_t)node * 8 + fl], di);  // self: di*h[n]

  int e = be.x;
  const int eend = be.y;
  for (; e + 3 < eend; e += 4) {
    int c0 = col[e], c1 = col[e + 1], c2 = col[e + 2], c3 = col[e + 3];
    uint4 u0 = plane[(size_t)c0 * 8 + fl];
    uint4 u1 = plane[(size_t)c1 * 8 + fl];
    uint4 u2 = plane[(size_t)c2 * 8 + fl];
    uint4 u3 = plane[(size_t)c3 * 8 + fl];
    float w0 = dinv[c0], w1 = dinv[c1], w2 = dinv[c2], w3 = dinv[c3];
    acc_row8s(ax, u0, w0); acc_row8s(ax, u1, w1);
    acc_row8s(ax, u2, w2); acc_row8s(ax, u3, w3);
  }
  for (; e < eend; ++e) {
    int c = col[e];
    acc_row8s(ax, plane[(size_t)c * 8 + fl], dinv[c]);
  }

  // epilogue: relu + projection over own 8 feats, reduce across the 8-lane group
  float s1 = 0.f, s2 = 0.f;
#pragma unroll
  for (int j = 0; j < 8; ++j) {
    int f = half * 64 + fl * 8 + j;
    float h = fmaxf(di * ax[j] + b1[f], 0.f);
    s1 += h * uv[f];
    s2 += h * uv[128 + f];
  }
#pragma unroll
  for (int o = 1; o < 8; o <<= 1) {
    s1 += __shfl_xor(s1, o);
    s2 += __shfl_xor(s2, o);
  }
  if (fl == 0 && valid) qpart[(size_t)half * NN + node] = make_float2(di * s1, di * s2);
}

// ---------------- qred: q[n] = qpart[0][n] + qpart[1][n] ----------------
__global__ void k_qred(const float2* __restrict__ qpart, float2* __restrict__ q, int n) {
  int i = blockIdx.x * 256 + threadIdx.x;
  if (i < n) {
    float2 a = qpart[i];
    float2 b = qpart[(size_t)NN + i];
    q[i] = make_float2(a.x + b.x, a.y + b.y);
  }
}

// ---------------- qagg: conv2+score collapsed (q table 800KB, L2-resident) ----------------
// Degree-sorted thread->node mapping (sortOrd) for wave-uniform inner-loop lengths.
#define LOADQ(P0, P1, P2, P3, pos)                                     \
  {                                                                    \
    P0 = q[col[(pos)]]; P1 = q[col[(pos) + 1]];                        \
    P2 = q[col[(pos) + 2]]; P3 = q[col[(pos) + 3]];                    \
  }
__global__ __launch_bounds__(256) void k_qagg(const float2* __restrict__ q,
                                              const float* __restrict__ dinv,
                                              const int2* __restrict__ rows,
                                              const int* __restrict__ col,
                                              const int* __restrict__ sortOrd,
                                              const float* __restrict__ uv,
                                              float2* __restrict__ sv) {
  const int idx = blockIdx.x * 256 + threadIdx.x;   // grid covers NB*NPB = 100096
  const int g = idx >> 7;
  const int node = g * NPB + sortOrd[idx];
  if (node >= NN) return;
  int2 be = rows[node];
  float2 a = q[node];
  float a1 = a.x, a2 = a.y;
  int e = be.x;
  const int eend = be.y;
  int n4 = (eend - e) >> 2;
  int ep = e;
  e += n4 << 2;
  if (n4) {
    float2 A0, A1, A2, A3, B0, B1, B2, B3;
    LOADQ(A0, A1, A2, A3, ep); ep += 4; n4--;
    while (n4 >= 2) {
      LOADQ(B0, B1, B2, B3, ep); ep += 4;
      a1 += (A0.x + A1.x) + (A2.x + A3.x);
      a2 += (A0.y + A1.y) + (A2.y + A3.y);
      LOADQ(A0, A1, A2, A3, ep); ep += 4;
      a1 += (B0.x + B1.x) + (B2.x + B3.x);
      a2 += (B0.y + B1.y) + (B2.y + B3.y);
      n4 -= 2;
    }
    if (n4) {
      LOADQ(B0, B1, B2, B3, ep);
      a1 += (A0.x + A1.x) + (A2.x + A3.x);
      a2 += (A0.y + A1.y) + (A2.y + A3.y);
      a1 += (B0.x + B1.x) + (B2.x + B3.x);
      a2 += (B0.y + B1.y) + (B2.y + B3.y);
    } else {
      a1 += (A0.x + A1.x) + (A2.x + A3.x);
      a2 += (A0.y + A1.y) + (A2.y + A3.y);
    }
  }
  for (; e < eend; ++e) {
    float2 qq = q[col[e]];
    a1 += qq.x; a2 += qq.y;
  }
  float di = dinv[node];
  sv[node] = make_float2(a1 * di + uv[256], a2 * di + uv[257]);
}

// ---------------- pair outputs: 2 pairs/thread, int2/float2 coalesced ----------------
__global__ void k_pairs(const float2* __restrict__ s, const int* __restrict__ I,
                        const int* __restrict__ J, const float* __restrict__ blin,
                        float* __restrict__ out, int np) {
  int p0 = (blockIdx.x * 256 + threadIdx.x) * 2;
  if (p0 + 1 < np) {
    int2 ii = *(const int2*)(I + p0);
    int2 jj = *(const int2*)(J + p0);
    float b = blin[0];
    float v0 = s[ii.x].x + s[jj.x].y + b;
    float v1 = s[ii.y].x + s[jj.y].y + b;
    *(float2*)(out + p0) = make_float2(1.f / (1.f + __expf(-v0)),
                                       1.f / (1.f + __expf(-v1)));
  } else if (p0 < np) {
    float v = s[I[p0]].x + s[J[p0]].y + blin[0];
    out[p0] = 1.f / (1.f + __expf(-v));
  }
}

extern "C" void kernel_launch(void* const* d_in, const int* in_sizes, int n_in,
                              void* d_out, int out_size, void* d_ws, size_t ws_size,
                              hipStream_t stream) {
  const float* x     = (const float*)d_in[0];
  const int*   eidx  = (const int*)d_in[1];
  const int*   Iidx  = (const int*)d_in[2];
  const int*   Jidx  = (const int*)d_in[3];
  const float* W1    = (const float*)d_in[4];
  const float* b1    = (const float*)d_in[5];
  const float* W2    = (const float*)d_in[6];
  const float* b2    = (const float*)d_in[7];
  const float* Wlin  = (const float*)d_in[8];
  const float* blin  = (const float*)d_in[9];
  const int* src = eidx;
  const int* dst = eidx + NE;

  // workspace layout: hs FIRST so half-rows are 128B-aligned (one line each)
  unsigned short* hs = (unsigned short*)d_ws;         // NN*HD bf16 = 25.6 MB (2 halves)
  float* dinv  = (float*)(hs + (size_t)NN * HD);      // 100000
  float* sv    = dinv + 100000;                       // 200000 (float2/node)
  float* qbuf  = sv + 200000;                         // 200000 (float2/node)
  float* qpart = qbuf + 200000;                       // 2*NN float2 = 400000
  float* uv    = qpart + 400000;                      // 264
  unsigned short* wt1 = (unsigned short*)(uv + 264);  // 16384 bf16
  int2* rows   = (int2*)(wt1 + 16384);                // NN int2 (8B-aligned)
  int* col     = (int*)(rows + NN);                   // NB*CAP = 2001920
  int* gcursor = col + NB * CAP;                      // NB (pad 784)
  int* sortOrd = gcursor + 784;                       // NB*NPB = 100096
  unsigned* binned = (unsigned*)(sortOrd + NB * NPB); // NB*CAP x 4B

  float* out = (float*)d_out;

  // ---- prep (weight prep + cursor init, fused) ----
  k_prep<<<66, 256, 0, stream>>>(W1, wt1, W2, Wlin, b2, uv, gcursor);

  // ---- GEMM (unscaled) || binA, one dispatch, roles interleaved ----
  k_fusedAG<<<GEMMB + NWG, 256, 0, stream>>>(x, wt1, hs, src, dst, gcursor, binned);

  // ---- binB: rows/col/dinv/sortOrd ----
  k_binB<<<NB, 256, 0, stream>>>(binned, gcursor, rows, col, dinv, sortOrd);

  // conv1 aggregation + relu + score projection (8 lanes/node, per-edge dinv[src])
  k_gatherR<<<NB * 8, 256, 0, stream>>>((const uint4*)hs, dinv, rows, col,
                                        sortOrd, b1, uv, (float2*)qpart);
  k_qred<<<(NN + 255) / 256, 256, 0, stream>>>((const float2*)qpart, (float2*)qbuf, NN);

  // conv2 + score head collapsed (degree-sorted)
  k_qagg<<<(NB * NPB) / 256, 256, 0, stream>>>((const float2*)qbuf, dinv, rows, col,
                                               sortOrd, uv, (float2*)sv);

  // pair outputs (2/thread)
  k_pairs<<<(NP / 2 + 255) / 256, 256, 0, stream>>>((const float2*)sv, Iidx, Jidx, blin, out, NP);
}